// Round 3
// baseline (269.872 us; speedup 1.0000x reference)
//
#include <hip/hip_runtime.h>
#include <cstdint>

#define DEV __device__ __forceinline__

typedef float f32x4 __attribute__((ext_vector_type(4)));
typedef short s16x8 __attribute__((ext_vector_type(8)));

DEV unsigned short f2bf(float f){
    unsigned u = __builtin_bit_cast(unsigned, f);
    u = u + 0x7fffu + ((u >> 16) & 1u);   // RNE
    return (unsigned short)(u >> 16);
}
DEV float bf2f(unsigned short h){
    unsigned u = ((unsigned)h) << 16;
    return __builtin_bit_cast(float, u);
}

typedef const void __attribute__((address_space(1)))* gcp;
typedef void __attribute__((address_space(3)))* lp;
DEV void gload_lds16(const void* g, void* l){
    // async global->LDS, 16B per lane; LDS dest = wave-uniform base + lane*16
    __builtin_amdgcn_global_load_lds((gcp)g, (lp)l, 16, 0, 0);
}

// ---------------------------------------------------------------------------
// Prep (1 block, ~4us): dragon pattern + blend.
// Optimizations vs old: normalize folded into next expand (lo/rden carried),
// min/max via wave shfl + 8-slot LDS (3 syncs/iter instead of ~16).
// pattern[11] has length 4095 = 2*2048-1 -> np.interp picks element 2i.
// ---------------------------------------------------------------------------
__global__ __launch_bounds__(256) void k_prep(
    const float* __restrict__ scale, const float* __restrict__ bias,
    const float* __restrict__ w1, const float* __restrict__ b1,
    const float* __restrict__ w2, const float* __restrict__ b2,
    float* __restrict__ dragon_w, float* __restrict__ blend_out)
{
    __shared__ float A[4095];
    __shared__ float Bb[4095];
    __shared__ float red[8];      // [0..3] wave mins, [4..7] wave maxs
    int tid = threadIdx.x;
    int lane = tid & 63, w = tid >> 6;

    if (tid == 0) A[0] = 0.5f;
    __syncthreads();
    float lo = 0.f, rden = 1.f;   // patterns[0] is used raw (no normalize)
    int len = 1;
    const float third = 1.0f/3.0f;
    for (int it = 1; it < 12; ++it){
        int n = len, nl = 2*n + 1;
        // expand, applying the carried normalization of A on the fly
        for (int i = tid; i < nl; i += 256){
            float v;
            if (i < n)       v = (A[i] - lo) * rden;
            else if (i == n) v = 0.5f;
            else             v = 1.0f - (A[2*n - i] - lo) * rden;
            Bb[i] = v;
        }
        __syncthreads();
        // conv [1/3,1/3,1/3] zero-pad 'same'; fuse local min/max
        float mn = 3.4e38f, mx = -3.4e38f;
        for (int i = tid; i < nl; i += 256){
            float s = Bb[i];
            if (i > 0)    s += Bb[i-1];
            if (i < nl-1) s += Bb[i+1];
            s *= third;
            A[i] = s;
            mn = fminf(mn, s); mx = fmaxf(mx, s);
        }
        #pragma unroll
        for (int off = 32; off > 0; off >>= 1){
            mn = fminf(mn, __shfl_xor(mn, off, 64));
            mx = fmaxf(mx, __shfl_xor(mx, off, 64));
        }
        if (lane == 0){ red[w] = mn; red[4 + w] = mx; }
        __syncthreads();
        mn = fminf(fminf(red[0], red[1]), fminf(red[2], red[3]));
        mx = fmaxf(fmaxf(red[4], red[5]), fmaxf(red[6], red[7]));
        lo = mn; rden = 1.0f / (mx - mn + 1e-8f);
        len = nl;
        __syncthreads();   // protects red[] and Bb for next iteration
    }
    // dragon_w[s] = softplus(normpat[2s]*scale[11] + bias[11])
    float sc = scale[11], bi = bias[11];
    for (int i = tid; i < 2048; i += 256){
        float x = (A[2*i] - lo) * rden * sc + bi;
        dragon_w[i] = fmaxf(x, 0.f) + log1pf(__expf(-fabsf(x)));
    }
    // blend = sigmoid(relu(w1[11,:]+b1) @ w2 + b2)
    if (tid < 64){
        float h = fmaxf(w1[11*64 + tid] + b1[tid], 0.f);
        float c = h * w2[tid];
        for (int off = 32; off > 0; off >>= 1) c += __shfl_xor(c, off, 64);
        if (tid == 0) blend_out[0] = 1.f/(1.f + __expf(-(c + b2[0])));
    }
}

// ---------------------------------------------------------------------------
// Conv (grid 3072): blocks 0..1023: Q->bf16 and K*w->bf16 (memory-bound,
// 128MB read / 32MB write). blocks 1024..3071: V -> Vt (bf16 [b][d][s]) +
// race-free vmean partials (reduced later inside k_gemm_qk).
// ---------------------------------------------------------------------------
__global__ __launch_bounds__(256) void k_conv(
    const float* __restrict__ Q, const float* __restrict__ K,
    const float* __restrict__ V, const float* __restrict__ dragon_w,
    unsigned short* __restrict__ Qb, unsigned short* __restrict__ Kb,
    unsigned short* __restrict__ Vt, float* __restrict__ vmean_part)
{
    __shared__ float sh[4480];    // V path: 64x66 tile + 256 red
    int tid = threadIdx.x;
    int bx  = blockIdx.x;

    if (bx < 1024){
        const long long total4 = (long long)8*2048*512/4;   // 2097152
        long long stride = 1024LL*256;
        for (long long i = (long long)bx*256 + tid; i < total4; i += stride){
            long long base = i*4;
            int s = (int)((base >> 9) & 2047);
            float wv = dragon_w[s];
            const float4 q = *(const float4*)(Q + base);
            const float4 k = *(const float4*)(K + base);
            ushort4 qo, ko;
            qo.x = f2bf(q.x);    qo.y = f2bf(q.y);    qo.z = f2bf(q.z);    qo.w = f2bf(q.w);
            ko.x = f2bf(k.x*wv); ko.y = f2bf(k.y*wv); ko.z = f2bf(k.z*wv); ko.w = f2bf(k.w*wv);
            *(ushort4*)(Qb + base) = qo;
            *(ushort4*)(Kb + base) = ko;
        }
        return;
    }

    // ---- V transpose + vmean partials ----
    int t = bx - 1024;                    // 0..2047 = 32 stile x 8 dtile x 8 b
    int stile = t & 31, dtile = (t >> 5) & 7, b = t >> 8;
    int s0 = stile*64, d0 = dtile*64;
    float (*tile)[66] = (float(*)[66])sh;  // 64x66 = 4224 floats
    float* red = sh + 4224;                // 256 floats
    int tx = tid & 63, ty = tid >> 6;
    const float* src = V + ((long long)b*2048 + s0)*512 + d0;
    #pragma unroll
    for (int r = 0; r < 16; ++r){
        int row = r*4 + ty;
        tile[row][tx] = src[(long long)row*512 + tx];
    }
    __syncthreads();
    unsigned short* dst = Vt + ((long long)b*512 + d0)*2048 + s0;
    #pragma unroll
    for (int r = 0; r < 16; ++r){
        int drow = r*4 + ty;
        dst[(long long)drow*2048 + tx] = f2bf(tile[tx][drow]);
    }
    // vmean partial: sum over the 64 s-rows of this tile (race-free per stile)
    int dcol = tid & 63, sp = tid >> 6;
    float s = 0.f;
    #pragma unroll
    for (int ii = 0; ii < 16; ++ii) s += tile[sp*16 + ii][dcol];
    red[sp*64 + dcol] = s;
    __syncthreads();
    if (sp == 0){
        float tot = red[dcol] + red[64+dcol] + red[128+dcol] + red[192+dcol];
        vmean_part[stile*4096 + b*512 + d0 + dcol] = tot * (1.0f/2048.0f);
    }
}

// ---------------------------------------------------------------------------
// GEMM 1: Sp[b,q,k] = bf16( exp( (Qb . Kb^T) / sqrt(512) ) )
// 128x128 tile, BK=64, 4 waves (2x2), 4x4 MFMA 16x16x32 per wave.
// LDS XOR-swizzled (row r chunk c holds global chunk c^(r&7)) -> 0 conflicts.
// Blocks (x==0,y==0) additionally reduce vmean partials (overlapped, free).
// ---------------------------------------------------------------------------
#define SCALE_QK 0.04419417382415922f

__global__ __launch_bounds__(256) void k_gemm_qk(
    const unsigned short* __restrict__ Qb, const unsigned short* __restrict__ Kb,
    const float* __restrict__ vmean_part, float* __restrict__ vmean,
    unsigned short* __restrict__ Sp)
{
    __shared__ unsigned short At[128*64];
    __shared__ unsigned short Bt[128*64];
    int tid = threadIdx.x;
    int lane = tid & 63, wave = tid >> 6;
    int wm = wave >> 1, wn = wave & 1;
    int ln = lane & 15, q4 = lane >> 4;
    int sx = ln & 7;                      // fragment-row swizzle key
    int q0 = blockIdx.y*128, k0 = blockIdx.x*128, b = blockIdx.z;

    // vmean reduction piggy-back: 8 blocks x 256 threads cover 4096 entries x2
    if (blockIdx.x == 0 && blockIdx.y == 0){
        #pragma unroll
        for (int rep = 0; rep < 2; ++rep){
            int idx = b*512 + rep*256 + tid;
            float s = 0.f;
            #pragma unroll
            for (int st = 0; st < 32; ++st) s += vmean_part[st*4096 + idx];
            vmean[idx] = s;
        }
    }

    const unsigned short* Abase = Qb + ((long long)b*2048 + q0)*512;
    const unsigned short* Bbase = Kb + ((long long)b*2048 + k0)*512;

    f32x4 acc[4][4];
    #pragma unroll
    for (int i = 0; i < 4; ++i)
        #pragma unroll
        for (int j = 0; j < 4; ++j) acc[i][j] = (f32x4)0.0f;

    int cc = lane & 7;                    // staging chunk col (LDS side)
    int rg = lane >> 3;                   // staging row within 8-row group
    for (int kt = 0; kt < 8; ++kt){
        #pragma unroll
        for (int c = 0; c < 4; ++c){
            int chunk = wave*4 + c;                 // 16 x 1KB chunks per tile
            int row = chunk*8 + rg;
            int gc  = cc ^ (row & 7);               // swizzled source chunk
            gload_lds16(Abase + (long long)row*512 + kt*64 + gc*8, &At[chunk*512]);
            gload_lds16(Bbase + (long long)row*512 + kt*64 + gc*8, &Bt[chunk*512]);
        }
        __syncthreads();
        #pragma unroll
        for (int ks = 0; ks < 2; ++ks){
            s16x8 af[4], bfr[4];
            int cs = ((ks*4 + q4) ^ sx) * 8;        // swizzled fragment chunk
            #pragma unroll
            for (int i = 0; i < 4; ++i)
                af[i] = *(const s16x8*)&At[(wm*64 + i*16 + ln)*64 + cs];
            #pragma unroll
            for (int j = 0; j < 4; ++j)
                bfr[j] = *(const s16x8*)&Bt[(wn*64 + j*16 + ln)*64 + cs];
            #pragma unroll
            for (int i = 0; i < 4; ++i)
                #pragma unroll
                for (int j = 0; j < 4; ++j)
                    acc[i][j] = __builtin_amdgcn_mfma_f32_16x16x32_bf16(af[i], bfr[j], acc[i][j], 0, 0, 0);
        }
        __syncthreads();
    }
    unsigned short* outp = Sp + (long long)b*2048*2048;
    #pragma unroll
    for (int i = 0; i < 4; ++i){
        #pragma unroll
        for (int j = 0; j < 4; ++j){
            #pragma unroll
            for (int r = 0; r < 4; ++r){
                int q = q0 + wm*64 + i*16 + q4*4 + r;   // C/D: row=(lane>>4)*4+reg
                int k = k0 + wn*64 + j*16 + ln;         //      col=lane&15
                float v = __expf(acc[i][j][r] * SCALE_QK);
                outp[(long long)q*2048 + k] = f2bf(v);
            }
        }
    }
}

// ---------------------------------------------------------------------------
// GEMM 2: out[b,q,d] = blend * (Sp . V) / l[q] + (1-blend) * Vmean[d]
// l[q] = sum_k Sp[q,k] accumulated from the A-fragments (wn==0 waves only).
// Same XOR-swizzled LDS as gemm_qk.
// ---------------------------------------------------------------------------
__global__ __launch_bounds__(256) void k_gemm_pv(
    const unsigned short* __restrict__ Sp, const unsigned short* __restrict__ Vt,
    const float* __restrict__ vmean, const float* __restrict__ blendp,
    float* __restrict__ out)
{
    __shared__ unsigned short At[128*64];
    __shared__ unsigned short Bt[128*64];
    __shared__ float l_sh[128];
    int tid = threadIdx.x;
    int lane = tid & 63, wave = tid >> 6;
    int wm = wave >> 1, wn = wave & 1;
    int ln = lane & 15, q4 = lane >> 4;
    int sx = ln & 7;
    int q0 = blockIdx.y*128, d0 = blockIdx.x*128, b = blockIdx.z;
    const unsigned short* Abase = Sp + (long long)b*2048*2048 + (long long)q0*2048;
    const unsigned short* Bbase = Vt + ((long long)b*512 + d0)*2048;

    f32x4 acc[4][4];
    #pragma unroll
    for (int i = 0; i < 4; ++i)
        #pragma unroll
        for (int j = 0; j < 4; ++j) acc[i][j] = (f32x4)0.0f;
    float lsum[4] = {0.f, 0.f, 0.f, 0.f};

    int cc = lane & 7;
    int rg = lane >> 3;
    for (int kt = 0; kt < 32; ++kt){
        #pragma unroll
        for (int c = 0; c < 4; ++c){
            int chunk = wave*4 + c;
            int row = chunk*8 + rg;
            int gc  = cc ^ (row & 7);
            gload_lds16(Abase + (long long)row*2048 + kt*64 + gc*8, &At[chunk*512]);
            gload_lds16(Bbase + (long long)row*2048 + kt*64 + gc*8, &Bt[chunk*512]);
        }
        __syncthreads();
        #pragma unroll
        for (int ks = 0; ks < 2; ++ks){
            s16x8 af[4], bfr[4];
            int cs = ((ks*4 + q4) ^ sx) * 8;
            #pragma unroll
            for (int i = 0; i < 4; ++i)
                af[i] = *(const s16x8*)&At[(wm*64 + i*16 + ln)*64 + cs];
            #pragma unroll
            for (int j = 0; j < 4; ++j)
                bfr[j] = *(const s16x8*)&Bt[(wn*64 + j*16 + ln)*64 + cs];
            if (wn == 0){
                // A-frag: lane holds P[m=ln][k..k+7] -> row sums for l
                #pragma unroll
                for (int i = 0; i < 4; ++i){
                    float s = 0.f;
                    #pragma unroll
                    for (int jj = 0; jj < 8; ++jj) s += bf2f((unsigned short)af[i][jj]);
                    lsum[i] += s;
                }
            }
            #pragma unroll
            for (int i = 0; i < 4; ++i)
                #pragma unroll
                for (int j = 0; j < 4; ++j)
                    acc[i][j] = __builtin_amdgcn_mfma_f32_16x16x32_bf16(af[i], bfr[j], acc[i][j], 0, 0, 0);
        }
        __syncthreads();
    }
    if (wn == 0){
        #pragma unroll
        for (int i = 0; i < 4; ++i){
            float v = lsum[i];
            v += __shfl_xor(v, 16, 64);
            v += __shfl_xor(v, 32, 64);
            if (lane < 16) l_sh[wm*64 + i*16 + lane] = v;
        }
    }
    __syncthreads();

    float blend = blendp[0];
    float ib = 1.0f - blend;
    float* obase = out + ((long long)b*2048 + q0)*512 + d0;
    float vm[4];
    #pragma unroll
    for (int j = 0; j < 4; ++j) vm[j] = vmean[b*512 + d0 + wn*64 + j*16 + ln];
    #pragma unroll
    for (int i = 0; i < 4; ++i){
        #pragma unroll
        for (int r = 0; r < 4; ++r){
            int ql = wm*64 + i*16 + q4*4 + r;
            float linv = 1.0f / l_sh[ql];
            #pragma unroll
            for (int j = 0; j < 4; ++j){
                int dl = wn*64 + j*16 + ln;
                obase[(long long)ql*512 + dl] = blend*acc[i][j][r]*linv + ib*vm[j];
            }
        }
    }
}

// ---------------------------------------------------------------------------
extern "C" void kernel_launch(void* const* d_in, const int* in_sizes, int n_in,
                              void* d_out, int out_size, void* d_ws, size_t ws_size,
                              hipStream_t stream)
{
    (void)in_sizes; (void)n_in; (void)out_size; (void)ws_size;
    const float* Q  = (const float*)d_in[0];
    const float* K  = (const float*)d_in[1];
    const float* V  = (const float*)d_in[2];
    const float* ps = (const float*)d_in[3];
    const float* pb = (const float*)d_in[4];
    const float* w1 = (const float*)d_in[5];
    const float* b1 = (const float*)d_in[6];
    const float* w2 = (const float*)d_in[7];
    const float* b2 = (const float*)d_in[8];
    float* out = (float*)d_out;

    char* ws = (char*)d_ws;
    float* dragon_w        = (float*)(ws);                                        // 8 KiB
    float* blend           = (float*)(ws + 8192);
    float* vmean           = (float*)(ws + 16384);                                // 16 KiB
    float* vmean_part      = (float*)(ws + 32768);                                // 512 KiB
    size_t off = 32768 + (size_t)512*1024;
    unsigned short* Qb     = (unsigned short*)(ws + off);                         // 16 MiB
    unsigned short* Kb     = (unsigned short*)(ws + off + (size_t)16*1024*1024);  // 16 MiB
    unsigned short* Vt     = (unsigned short*)(ws + off + (size_t)32*1024*1024);  // 16 MiB
    unsigned short* Sp     = (unsigned short*)(ws + off + (size_t)48*1024*1024);  // 64 MiB

    hipLaunchKernelGGL(k_prep,    dim3(1),         dim3(256), 0, stream,
                       ps, pb, w1, b1, w2, b2, dragon_w, blend);
    hipLaunchKernelGGL(k_conv,    dim3(3072),      dim3(256), 0, stream,
                       Q, K, V, dragon_w, Qb, Kb, Vt, vmean_part);
    hipLaunchKernelGGL(k_gemm_qk, dim3(16, 16, 8), dim3(256), 0, stream,
                       Qb, Kb, vmean_part, vmean, Sp);
    hipLaunchKernelGGL(k_gemm_pv, dim3(4, 16, 8),  dim3(256), 0, stream,
                       Sp, Vt, vmean, blend, out);
}